// Round 2
// baseline (402.264 us; speedup 1.0000x reference)
//
#include <hip/hip_runtime.h>
#include <hip/hip_bf16.h>

using bf16 = __hip_bfloat16;
typedef short bf16x8 __attribute__((ext_vector_type(8)));
typedef float f32x4 __attribute__((ext_vector_type(4)));

#define DD 256
#define MTOT 65536   // B*QH*QW = 16*64*64

static __device__ __forceinline__ short f2bs(float f) {
    bf16 h = __float2bfloat16(f);          // RNE
    return *reinterpret_cast<short*>(&h);
}
static __device__ __forceinline__ float bs2f(short s) {
    bf16 h = *reinterpret_cast<bf16*>(&s);
    return __bfloat162float(h);
}

// ---------------- K0: convert+transpose weights (f32 -> bf16) ----------------
// Wb,Wk,Wm 256x256 ; Woff 256x64 + WA 256x32 -> WoffAT [96][256]
__global__ __launch_bounds__(256) void k_transpose(
    const float* __restrict__ Wb, const float* __restrict__ Wk, const float* __restrict__ Wm,
    const float* __restrict__ Woff, const float* __restrict__ WA,
    bf16* __restrict__ WbT, bf16* __restrict__ WkT, bf16* __restrict__ WmT,
    bf16* __restrict__ WoffAT)
{
    int idx = blockIdx.x * 256 + threadIdx.x;
    if (idx < 3 * 65536) {
        int which = idx >> 16, e = idx & 65535;
        int i = e >> 8, j = e & 255;               // in[i][j]
        const float* src = which == 0 ? Wb : (which == 1 ? Wk : Wm);
        bf16*        dst = which == 0 ? WbT : (which == 1 ? WkT : WmT);
        dst[j * 256 + i] = __float2bfloat16(src[e]);
    } else {
        int e = idx - 3 * 65536;
        if (e < 96 * 256) {
            int j = e >> 8, i = e & 255;           // out row j (orig col), k = i
            WoffAT[j * 256 + i] = __float2bfloat16((j < 64) ? Woff[i * 64 + j]
                                                            : WA[i * 32 + (j - 64)]);
        }
    }
}

// ---------------- shared MFMA mainloop ----------------
// Wave owns 32 A-rows x NT*16 cols. A: [M][256] (f32 or bf16); BT: [N][256] bf16.
// mfma_f32_16x16x32_bf16 layouts (m89/m91-verified):
//   A-frag: row = lane&15, k = (lane>>4)*8 + e ;  B-frag: col = lane&15, same k
//   C/D   : col = lane&15, row = (lane>>4)*4 + reg
template <int NT, bool AF32>
static __device__ __forceinline__ void gemm_mainloop(
    const void* __restrict__ Av, const bf16* __restrict__ BT,
    int arow0, int lane, f32x4 (&acc)[2][NT])
{
    const int rsub = lane & 15;
    const int kg   = (lane >> 4) * 8;
    const bf16* bp = BT + (size_t)rsub * DD + kg;
#pragma unroll
    for (int kk = 0; kk < DD; kk += 32) {
        bf16x8 a0, a1;
        if constexpr (AF32) {
            const float* ap = (const float*)Av + (size_t)(arow0 + rsub) * DD + kg;
            f32x4 v0 = *(const f32x4*)(ap + kk);
            f32x4 v1 = *(const f32x4*)(ap + kk + 4);
            f32x4 w0 = *(const f32x4*)(ap + 16 * DD + kk);
            f32x4 w1 = *(const f32x4*)(ap + 16 * DD + kk + 4);
#pragma unroll
            for (int e = 0; e < 4; ++e) {
                a0[e] = f2bs(v0[e]); a0[e + 4] = f2bs(v1[e]);
                a1[e] = f2bs(w0[e]); a1[e + 4] = f2bs(w1[e]);
            }
        } else {
            const bf16* ap = (const bf16*)Av + (size_t)(arow0 + rsub) * DD + kg;
            a0 = *(const bf16x8*)(ap + kk);
            a1 = *(const bf16x8*)(ap + 16 * DD + kk);
        }
#pragma unroll
        for (int nt = 0; nt < NT; ++nt) {
            bf16x8 b = *(const bf16x8*)(bp + (size_t)nt * 16 * DD + kk);
            acc[0][nt] = __builtin_amdgcn_mfma_f32_16x16x32_bf16(a0, b, acc[0][nt], 0, 0, 0);
            acc[1][nt] = __builtin_amdgcn_mfma_f32_16x16x32_bf16(a1, b, acc[1][nt], 0, 0, 0);
        }
    }
}

// ---------------- K1: sq = src_query @ Wb + bb  -> bf16 [65536][256] ----------------
__global__ __launch_bounds__(256) void k_gemm_sq(
    const float* __restrict__ src, const bf16* __restrict__ WbT,
    const float* __restrict__ bb, bf16* __restrict__ sq)
{
    int wave = threadIdx.x >> 6, lane = threadIdx.x & 63;
    int row0 = blockIdx.x * 128 + wave * 32;
    f32x4 acc[2][16] = {};
    gemm_mainloop<16, true>(src, WbT, row0, lane, acc);
    int col = lane & 15;
    int rb  = row0 + ((lane >> 4) << 2);
#pragma unroll
    for (int mt = 0; mt < 2; ++mt)
#pragma unroll
        for (int nt = 0; nt < 16; ++nt) {
            float bias = bb[nt * 16 + col];
#pragma unroll
            for (int r = 0; r < 4; ++r)
                sq[(size_t)(rb + mt * 16 + r) * DD + nt * 16 + col] =
                    __float2bfloat16(acc[mt][nt][r] + bias);
        }
}

// ---------------- K2: [off | A] = sq @ WoffAT^T + bias ; softmax(A) over K=4 per head ----
__global__ __launch_bounds__(256) void k_gemm_offA(
    const bf16* __restrict__ sq, const bf16* __restrict__ WoffAT,
    const float* __restrict__ boff, const float* __restrict__ bA,
    float* __restrict__ off_ws, float* __restrict__ A_ws)
{
    int wave = threadIdx.x >> 6, lane = threadIdx.x & 63;
    int row0 = blockIdx.x * 128 + wave * 32;
    f32x4 acc[2][6] = {};
    gemm_mainloop<6, false>(sq, WoffAT, row0, lane, acc);
    int col = lane & 15;
    int rb  = row0 + ((lane >> 4) << 2);
#pragma unroll
    for (int mt = 0; mt < 2; ++mt) {
#pragma unroll
        for (int nt = 0; nt < 4; ++nt) {        // offsets: cols 0..63
            float bias = boff[nt * 16 + col];
#pragma unroll
            for (int r = 0; r < 4; ++r) {
                int m = rb + mt * 16 + r;
                off_ws[(size_t)m * 64 + nt * 16 + col] = acc[mt][nt][r] + bias;
            }
        }
#pragma unroll
        for (int nt = 4; nt < 6; ++nt) {        // A logits: cols 64..95 -> a-col 0..31
            int ac = nt * 16 + col - 64;        // head = ac>>2, slot = ac&3
            float bias = bA[ac];
#pragma unroll
            for (int r = 0; r < 4; ++r) {
                int m = rb + mt * 16 + r;
                float v  = acc[mt][nt][r] + bias;
                // lanes (l^1, l^2) hold the same head's other 3 slots (cols 4h..4h+3)
                float mx = fmaxf(v, __shfl_xor(v, 1));
                mx       = fmaxf(mx, __shfl_xor(mx, 2));
                float e  = __expf(v - mx);
                float s  = e + __shfl_xor(e, 1);
                s       += __shfl_xor(s, 2);
                A_ws[(size_t)m * 32 + ac] = e / s;
            }
        }
    }
}

// ---------------- K3: kf = keys @ Wk + bk -> bf16 head-split [(b*8+h)*4096 + pix][32] ----
__global__ __launch_bounds__(256) void k_gemm_kf(
    const float* __restrict__ keys, const bf16* __restrict__ WkT,
    const float* __restrict__ bk, bf16* __restrict__ kf)
{
    int wave = threadIdx.x >> 6, lane = threadIdx.x & 63;
    int row0 = blockIdx.x * 128 + wave * 32;
    f32x4 acc[2][16] = {};
    gemm_mainloop<16, true>(keys, WkT, row0, lane, acc);
    int col = lane & 15;
    int rb  = row0 + ((lane >> 4) << 2);
#pragma unroll
    for (int mt = 0; mt < 2; ++mt)
#pragma unroll
        for (int nt = 0; nt < 16; ++nt) {
            int j = nt * 16 + col;             // head h=j>>5, channel c=j&31
            float bias = bk[j];
#pragma unroll
            for (int r = 0; r < 4; ++r) {
                int m = rb + mt * 16 + r;      // key pixel row: b = m>>12, pix = m&4095
                size_t dst = (((size_t)(m >> 12) * 8 + (j >> 5)) * 4096 + (m & 4095)) * 32 + (j & 31);
                kf[dst] = __float2bfloat16(acc[mt][nt][r] + bias);
            }
        }
}

// ---------------- K4: bilinear gather + weighted sum -> feat bf16 [65536][256] ----------------
__global__ __launch_bounds__(256) void k_sample(
    const float* __restrict__ ref_point, const float* __restrict__ off_ws,
    const float* __restrict__ A_ws, const bf16* __restrict__ kf,
    bf16* __restrict__ feat)
{
    int m = blockIdx.x;                 // query index
    int t = threadIdx.x;
    int h = t >> 5, c = t & 31;
    int b = m >> 12, pix = m & 4095;
    int rbatch = (b * 8 + h) & 15;      // faithful: tile() => ref batch = (b*H+h) % B
    float rx = ref_point[((size_t)rbatch * 4096 + pix) * 2 + 0] * 63.0f;
    float ry = ref_point[((size_t)rbatch * 4096 + pix) * 2 + 1] * 63.0f;
    const bf16* kfh = kf + ((size_t)(b * 8 + h) * 4096) * 32;
    float acc = 0.f;
#pragma unroll
    for (int k = 0; k < 4; ++k) {
        float ox = off_ws[(size_t)m * 64 + (h * 4 + k) * 2 + 0];
        float oy = off_ws[(size_t)m * 64 + (h * 4 + k) * 2 + 1];
        float a  = A_ws[(size_t)m * 32 + h * 4 + k];
        float px = (rx + ox) * (64.0f / 63.0f) - 0.5f;   // grid_sample unnormalize, align_corners=False
        float py = (ry + oy) * (64.0f / 63.0f) - 0.5f;
        float x0 = floorf(px), y0 = floorf(py);
        float wx1 = px - x0, wy1 = py - y0;
        int xi = (int)x0, yi = (int)y0;
        float s = 0.f;
        if (xi >= 0 && xi < 64 && yi >= 0 && yi < 64)
            s += (1.f - wx1) * (1.f - wy1) * __bfloat162float(kfh[(yi * 64 + xi) * 32 + c]);
        if (xi + 1 >= 0 && xi + 1 < 64 && yi >= 0 && yi < 64)
            s += wx1 * (1.f - wy1) * __bfloat162float(kfh[(yi * 64 + xi + 1) * 32 + c]);
        if (xi >= 0 && xi < 64 && yi + 1 >= 0 && yi + 1 < 64)
            s += (1.f - wx1) * wy1 * __bfloat162float(kfh[((yi + 1) * 64 + xi) * 32 + c]);
        if (xi + 1 >= 0 && xi + 1 < 64 && yi + 1 >= 0 && yi + 1 < 64)
            s += wx1 * wy1 * __bfloat162float(kfh[((yi + 1) * 64 + xi + 1) * 32 + c]);
        acc += a * s;
    }
    feat[(size_t)m * DD + h * 32 + c] = __float2bfloat16(acc);
}

// ---------------- K5: out = feat @ Wm + bm -> f32 ----------------
__global__ __launch_bounds__(256) void k_gemm_out(
    const bf16* __restrict__ feat, const bf16* __restrict__ WmT,
    const float* __restrict__ bm, float* __restrict__ out)
{
    int wave = threadIdx.x >> 6, lane = threadIdx.x & 63;
    int row0 = blockIdx.x * 128 + wave * 32;
    f32x4 acc[2][16] = {};
    gemm_mainloop<16, false>(feat, WmT, row0, lane, acc);
    int col = lane & 15;
    int rb  = row0 + ((lane >> 4) << 2);
#pragma unroll
    for (int mt = 0; mt < 2; ++mt)
#pragma unroll
        for (int nt = 0; nt < 16; ++nt) {
            float bias = bm[nt * 16 + col];
#pragma unroll
            for (int r = 0; r < 4; ++r)
                out[(size_t)(rb + mt * 16 + r) * DD + nt * 16 + col] =
                    acc[mt][nt][r] + bias;
        }
}

extern "C" void kernel_launch(void* const* d_in, const int* in_sizes, int n_in,
                              void* d_out, int out_size, void* d_ws, size_t ws_size,
                              hipStream_t stream)
{
    (void)in_sizes; (void)n_in; (void)out_size; (void)ws_size;
    // setup_inputs order (all float32):
    // 0 query (unused) 1 keys 2 ref_point 3 src_query 4 Wq 5 bq 6 Wb 7 bb
    // 8 Wk 9 bk 10 Woff 11 boff 12 WA 13 bA 14 Wm 15 bm
    const float* keys = (const float*)d_in[1];
    const float* refp = (const float*)d_in[2];
    const float* srcq = (const float*)d_in[3];
    const float* Wb   = (const float*)d_in[6];
    const float* bb   = (const float*)d_in[7];
    const float* Wk   = (const float*)d_in[8];
    const float* bk   = (const float*)d_in[9];
    const float* Woff = (const float*)d_in[10];
    const float* boff = (const float*)d_in[11];
    const float* WA   = (const float*)d_in[12];
    const float* bA   = (const float*)d_in[13];
    const float* Wm   = (const float*)d_in[14];
    const float* bm   = (const float*)d_in[15];

    char* ws = (char*)d_ws;
    bf16*  WbT    = (bf16*)(ws + 0);                    // 128 KiB
    bf16*  WkT    = (bf16*)(ws + 131072);               // 128 KiB
    bf16*  WmT    = (bf16*)(ws + 262144);               // 128 KiB
    bf16*  WoffAT = (bf16*)(ws + 393216);               // 48 KiB  [96][256]
    bf16*  sq_ws  = (bf16*)(ws + 442368);               // 32 MiB  [65536][256]
    bf16*  kf_ws  = (bf16*)(ws + 442368 + 33554432ull);             // 32 MiB
    bf16*  feat_ws= (bf16*)(ws + 442368 + 2ull * 33554432ull);      // 32 MiB
    float* off_ws = (float*)(ws + 442368 + 3ull * 33554432ull);     // 16 MiB  [65536][64]
    float* A_ws   = (float*)(ws + 442368 + 3ull * 33554432ull + 16777216ull); // 8 MiB [65536][32]

    float* out = (float*)d_out;

    k_transpose<<<864, 256, 0, stream>>>(Wb, Wk, Wm, Woff, WA, WbT, WkT, WmT, WoffAT);
    k_gemm_sq  <<<512, 256, 0, stream>>>(srcq, WbT, bb, sq_ws);
    k_gemm_kf  <<<512, 256, 0, stream>>>(keys, WkT, bk, kf_ws);
    k_gemm_offA<<<512, 256, 0, stream>>>(sq_ws, WoffAT, boff, bA, off_ws, A_ws);
    k_sample   <<<65536, 256, 0, stream>>>(refp, off_ws, A_ws, kf_ws, feat_ws);
    k_gemm_out <<<512, 256, 0, stream>>>(feat_ws, WmT, bm, out);
}

// Round 4
// 241.469 us; speedup vs baseline: 1.6659x; 1.6659x over previous
//
#include <hip/hip_runtime.h>
#include <hip/hip_bf16.h>

using bf16 = __hip_bfloat16;
typedef short bf16x8 __attribute__((ext_vector_type(8)));
typedef float f32x4 __attribute__((ext_vector_type(4)));

#define DD 256
#define MTOT 65536   // B*QH*QW = 16*64*64

static __device__ __forceinline__ short f2bs(float f) {
    bf16 h = __float2bfloat16(f);          // RNE
    return *reinterpret_cast<short*>(&h);
}
static __device__ __forceinline__ float bs2f(short s) {
    unsigned u = (unsigned)(unsigned short)s << 16;
    return __uint_as_float(u);
}

// ---------------- K0: convert+transpose weights (f32 -> bf16) ----------------
// Wb,Wk,Wm 256x256 ; Woff 256x64 + WA 256x32 -> WoffAT [96][256]
__global__ __launch_bounds__(256) void k_transpose(
    const float* __restrict__ Wb, const float* __restrict__ Wk, const float* __restrict__ Wm,
    const float* __restrict__ Woff, const float* __restrict__ WA,
    bf16* __restrict__ WbT, bf16* __restrict__ WkT, bf16* __restrict__ WmT,
    bf16* __restrict__ WoffAT)
{
    int idx = blockIdx.x * 256 + threadIdx.x;
    if (idx < 3 * 65536) {
        int which = idx >> 16, e = idx & 65535;
        int i = e >> 8, j = e & 255;               // in[i][j]
        const float* src = which == 0 ? Wb : (which == 1 ? Wk : Wm);
        bf16*        dst = which == 0 ? WbT : (which == 1 ? WkT : WmT);
        dst[j * 256 + i] = __float2bfloat16(src[e]);
    } else {
        int e = idx - 3 * 65536;
        if (e < 96 * 256) {
            int j = e >> 8, i = e & 255;           // out row j (orig col), k = i
            WoffAT[j * 256 + i] = __float2bfloat16((j < 64) ? Woff[i * 64 + j]
                                                            : WA[i * 32 + (j - 64)]);
        }
    }
}

// ---------------- shared MFMA mainloop ----------------
// Wave owns 32 A-rows x NT*16 cols. A: [M][256] (f32 or bf16); BT: [N][256] bf16.
// mfma_f32_16x16x32_bf16 layouts (m89/m91-verified):
//   A-frag: row = lane&15, k = (lane>>4)*8 + e ;  B-frag: col = lane&15, same k
//   C/D   : col = lane&15, row = (lane>>4)*4 + reg
template <int NT, bool AF32>
static __device__ __forceinline__ void gemm_mainloop(
    const void* __restrict__ Av, const bf16* __restrict__ BT,
    int arow0, int lane, f32x4 (&acc)[2][NT])
{
    const int rsub = lane & 15;
    const int kg   = (lane >> 4) * 8;
    const bf16* bp = BT + (size_t)rsub * DD + kg;
#pragma unroll
    for (int kk = 0; kk < DD; kk += 32) {
        bf16x8 a0, a1;
        if constexpr (AF32) {
            const float* ap = (const float*)Av + (size_t)(arow0 + rsub) * DD + kg;
            f32x4 v0 = *(const f32x4*)(ap + kk);
            f32x4 v1 = *(const f32x4*)(ap + kk + 4);
            f32x4 w0 = *(const f32x4*)(ap + 16 * DD + kk);
            f32x4 w1 = *(const f32x4*)(ap + 16 * DD + kk + 4);
#pragma unroll
            for (int e = 0; e < 4; ++e) {
                a0[e] = f2bs(v0[e]); a0[e + 4] = f2bs(v1[e]);
                a1[e] = f2bs(w0[e]); a1[e + 4] = f2bs(w1[e]);
            }
        } else {
            const bf16* ap = (const bf16*)Av + (size_t)(arow0 + rsub) * DD + kg;
            a0 = *(const bf16x8*)(ap + kk);
            a1 = *(const bf16x8*)(ap + 16 * DD + kk);
        }
#pragma unroll
        for (int nt = 0; nt < NT; ++nt) {
            bf16x8 b = *(const bf16x8*)(bp + (size_t)nt * 16 * DD + kk);
            acc[0][nt] = __builtin_amdgcn_mfma_f32_16x16x32_bf16(a0, b, acc[0][nt], 0, 0, 0);
            acc[1][nt] = __builtin_amdgcn_mfma_f32_16x16x32_bf16(a1, b, acc[1][nt], 0, 0, 0);
        }
    }
}

// ---------------- K1: sq = src_query @ Wb + bb  -> bf16 [65536][256] ----------------
__global__ __launch_bounds__(256) void k_gemm_sq(
    const float* __restrict__ src, const bf16* __restrict__ WbT,
    const float* __restrict__ bb, bf16* __restrict__ sq)
{
    int wave = threadIdx.x >> 6, lane = threadIdx.x & 63;
    int row0 = blockIdx.x * 128 + wave * 32;
    f32x4 acc[2][16] = {};
    gemm_mainloop<16, true>(src, WbT, row0, lane, acc);
    int col = lane & 15;
    int rb  = row0 + ((lane >> 4) << 2);
#pragma unroll
    for (int mt = 0; mt < 2; ++mt)
#pragma unroll
        for (int nt = 0; nt < 16; ++nt) {
            float bias = bb[nt * 16 + col];
#pragma unroll
            for (int r = 0; r < 4; ++r)
                sq[(size_t)(rb + mt * 16 + r) * DD + nt * 16 + col] =
                    __float2bfloat16(acc[mt][nt][r] + bias);
        }
}

// ---------------- K2: [off | A] = sq @ WoffAT^T + bias ; softmax(A) over K=4 per head ----
__global__ __launch_bounds__(256) void k_gemm_offA(
    const bf16* __restrict__ sq, const bf16* __restrict__ WoffAT,
    const float* __restrict__ boff, const float* __restrict__ bA,
    float* __restrict__ off_ws, float* __restrict__ A_ws)
{
    int wave = threadIdx.x >> 6, lane = threadIdx.x & 63;
    int row0 = blockIdx.x * 128 + wave * 32;
    f32x4 acc[2][6] = {};
    gemm_mainloop<6, false>(sq, WoffAT, row0, lane, acc);
    int col = lane & 15;
    int rb  = row0 + ((lane >> 4) << 2);
#pragma unroll
    for (int mt = 0; mt < 2; ++mt) {
#pragma unroll
        for (int nt = 0; nt < 4; ++nt) {        // offsets: cols 0..63
            float bias = boff[nt * 16 + col];
#pragma unroll
            for (int r = 0; r < 4; ++r) {
                int m = rb + mt * 16 + r;
                off_ws[(size_t)m * 64 + nt * 16 + col] = acc[mt][nt][r] + bias;
            }
        }
#pragma unroll
        for (int nt = 4; nt < 6; ++nt) {        // A logits: cols 64..95 -> a-col 0..31
            int ac = nt * 16 + col - 64;        // head = ac>>2, slot = ac&3
            float bias = bA[ac];
#pragma unroll
            for (int r = 0; r < 4; ++r) {
                int m = rb + mt * 16 + r;
                float v  = acc[mt][nt][r] + bias;
                // lanes (l^1, l^2) hold the same head's other 3 slots (cols 4h..4h+3)
                float mx = fmaxf(v, __shfl_xor(v, 1));
                mx       = fmaxf(mx, __shfl_xor(mx, 2));
                float e  = __expf(v - mx);
                float s  = e + __shfl_xor(e, 1);
                s       += __shfl_xor(s, 2);
                A_ws[(size_t)m * 32 + ac] = e / s;
            }
        }
    }
}

// ---------------- K3: kf = keys @ Wk + bk -> bf16 head-split [(b*8+h)*4096 + pix][32] ----
__global__ __launch_bounds__(256) void k_gemm_kf(
    const float* __restrict__ keys, const bf16* __restrict__ WkT,
    const float* __restrict__ bk, bf16* __restrict__ kf)
{
    int wave = threadIdx.x >> 6, lane = threadIdx.x & 63;
    int row0 = blockIdx.x * 128 + wave * 32;
    f32x4 acc[2][16] = {};
    gemm_mainloop<16, true>(keys, WkT, row0, lane, acc);
    int col = lane & 15;
    int rb  = row0 + ((lane >> 4) << 2);
#pragma unroll
    for (int mt = 0; mt < 2; ++mt)
#pragma unroll
        for (int nt = 0; nt < 16; ++nt) {
            int j = nt * 16 + col;             // head h=j>>5, channel c=j&31
            float bias = bk[j];
#pragma unroll
            for (int r = 0; r < 4; ++r) {
                int m = rb + mt * 16 + r;      // key pixel row: b = m>>12, pix = m&4095
                size_t dst = (((size_t)(m >> 12) * 8 + (j >> 5)) * 4096 + (m & 4095)) * 32 + (j & 31);
                kf[dst] = __float2bfloat16(acc[mt][nt][r] + bias);
            }
        }
}

// ---------------- K4: bilinear gather + weighted sum -> feat bf16 [65536][256] ----------------
// Block = 8 queries x 8 heads x 4 channel-groups (of 8 ch). Each lane: 16B bf16x8
// corner loads, branchless zero-padding via multiplicative validity masks.
__global__ __launch_bounds__(256) void k_sample(
    const float* __restrict__ ref_point, const float* __restrict__ off_ws,
    const float* __restrict__ A_ws, const bf16* __restrict__ kf,
    bf16* __restrict__ feat)
{
    int t  = threadIdx.x;
    int q  = t >> 5;             // 0..7
    int h  = (t >> 2) & 7;       // 0..7
    int cg = t & 3;              // 0..3 -> channels cg*8..cg*8+7
    int m  = blockIdx.x * 8 + q;
    int b  = m >> 12, pix = m & 4095;
    int rbatch = (b * 8 + h) & 15;      // faithful: tile() => ref batch = (b*H+h) % B
    const float* rp = ref_point + ((size_t)rbatch * 4096 + pix) * 2;
    float rx = rp[0] * 63.0f;
    float ry = rp[1] * 63.0f;
    const bf16* kfh = kf + ((size_t)(b * 8 + h) * 4096) * 32 + cg * 8;
    float acc[8] = {};
#pragma unroll
    for (int k = 0; k < 4; ++k) {
        const float* op = off_ws + (size_t)m * 64 + (h * 4 + k) * 2;
        float ox = op[0], oy = op[1];
        float a  = A_ws[(size_t)m * 32 + h * 4 + k];
        float px = (rx + ox) * (64.0f / 63.0f) - 0.5f;   // grid_sample unnormalize, align_corners=False
        float py = (ry + oy) * (64.0f / 63.0f) - 0.5f;
        float x0 = floorf(px), y0 = floorf(py);
        float wx1 = px - x0, wy1 = py - y0;
        int xi = (int)x0, yi = (int)y0;
        // validity folded into weights (padding_mode='zeros'), premultiplied by a
        float ax0 = (1.f - wx1) * ((xi     >= 0 && xi     < 64) ? 1.f : 0.f);
        float ax1 = wx1         * ((xi + 1 >= 0 && xi + 1 < 64) ? 1.f : 0.f);
        float ay0 = (1.f - wy1) * ((yi     >= 0 && yi     < 64) ? a : 0.f);
        float ay1 = wy1         * ((yi + 1 >= 0 && yi + 1 < 64) ? a : 0.f);
        int xc0 = min(max(xi, 0), 63),     xc1 = min(max(xi + 1, 0), 63);
        int yc0 = min(max(yi, 0), 63) * 64, yc1 = min(max(yi + 1, 0), 63) * 64;
        bf16x8 v00 = *(const bf16x8*)(kfh + (yc0 + xc0) * 32);
        bf16x8 v01 = *(const bf16x8*)(kfh + (yc0 + xc1) * 32);
        bf16x8 v10 = *(const bf16x8*)(kfh + (yc1 + xc0) * 32);
        bf16x8 v11 = *(const bf16x8*)(kfh + (yc1 + xc1) * 32);
        float w00 = ax0 * ay0, w01 = ax1 * ay0, w10 = ax0 * ay1, w11 = ax1 * ay1;
#pragma unroll
        for (int e = 0; e < 8; ++e) {
            acc[e] += w00 * bs2f(v00[e]) + w01 * bs2f(v01[e])
                    + w10 * bs2f(v10[e]) + w11 * bs2f(v11[e]);
        }
    }
    bf16x8 o;
#pragma unroll
    for (int e = 0; e < 8; ++e) o[e] = f2bs(acc[e]);
    *(bf16x8*)(feat + (size_t)m * DD + h * 32 + cg * 8) = o;
}

// ---------------- K5: out = feat @ Wm + bm -> f32 ----------------
__global__ __launch_bounds__(256) void k_gemm_out(
    const bf16* __restrict__ feat, const bf16* __restrict__ WmT,
    const float* __restrict__ bm, float* __restrict__ out)
{
    int wave = threadIdx.x >> 6, lane = threadIdx.x & 63;
    int row0 = blockIdx.x * 128 + wave * 32;
    f32x4 acc[2][16] = {};
    gemm_mainloop<16, false>(feat, WmT, row0, lane, acc);
    int col = lane & 15;
    int rb  = row0 + ((lane >> 4) << 2);
#pragma unroll
    for (int mt = 0; mt < 2; ++mt)
#pragma unroll
        for (int nt = 0; nt < 16; ++nt) {
            float bias = bm[nt * 16 + col];
#pragma unroll
            for (int r = 0; r < 4; ++r)
                out[(size_t)(rb + mt * 16 + r) * DD + nt * 16 + col] =
                    acc[mt][nt][r] + bias;
        }
}

extern "C" void kernel_launch(void* const* d_in, const int* in_sizes, int n_in,
                              void* d_out, int out_size, void* d_ws, size_t ws_size,
                              hipStream_t stream)
{
    (void)in_sizes; (void)n_in; (void)out_size; (void)ws_size;
    // setup_inputs order (all float32):
    // 0 query (unused) 1 keys 2 ref_point 3 src_query 4 Wq 5 bq 6 Wb 7 bb
    // 8 Wk 9 bk 10 Woff 11 boff 12 WA 13 bA 14 Wm 15 bm
    const float* keys = (const float*)d_in[1];
    const float* refp = (const float*)d_in[2];
    const float* srcq = (const float*)d_in[3];
    const float* Wb   = (const float*)d_in[6];
    const float* bb   = (const float*)d_in[7];
    const float* Wk   = (const float*)d_in[8];
    const float* bk   = (const float*)d_in[9];
    const float* Woff = (const float*)d_in[10];
    const float* boff = (const float*)d_in[11];
    const float* WA   = (const float*)d_in[12];
    const float* bA   = (const float*)d_in[13];
    const float* Wm   = (const float*)d_in[14];
    const float* bm   = (const float*)d_in[15];

    char* ws = (char*)d_ws;
    bf16*  WbT    = (bf16*)(ws + 0);                    // 128 KiB
    bf16*  WkT    = (bf16*)(ws + 131072);               // 128 KiB
    bf16*  WmT    = (bf16*)(ws + 262144);               // 128 KiB
    bf16*  WoffAT = (bf16*)(ws + 393216);               // 48 KiB  [96][256]
    bf16*  sq_ws  = (bf16*)(ws + 442368);               // 32 MiB  [65536][256]
    bf16*  kf_ws  = (bf16*)(ws + 442368 + 33554432ull);             // 32 MiB
    bf16*  feat_ws= (bf16*)(ws + 442368 + 2ull * 33554432ull);      // 32 MiB
    float* off_ws = (float*)(ws + 442368 + 3ull * 33554432ull);     // 16 MiB  [65536][64]
    float* A_ws   = (float*)(ws + 442368 + 3ull * 33554432ull + 16777216ull); // 8 MiB [65536][32]

    float* out = (float*)d_out;

    k_transpose<<<864, 256, 0, stream>>>(Wb, Wk, Wm, Woff, WA, WbT, WkT, WmT, WoffAT);
    k_gemm_sq  <<<512, 256, 0, stream>>>(srcq, WbT, bb, sq_ws);
    k_gemm_kf  <<<512, 256, 0, stream>>>(keys, WkT, bk, kf_ws);
    k_gemm_offA<<<512, 256, 0, stream>>>(sq_ws, WoffAT, boff, bA, off_ws, A_ws);
    k_sample   <<<8192, 256, 0, stream>>>(refp, off_ws, A_ws, kf_ws, feat_ws);
    k_gemm_out <<<512, 256, 0, stream>>>(feat_ws, WmT, bm, out);
}

// Round 5
// 213.755 us; speedup vs baseline: 1.8819x; 1.1297x over previous
//
#include <hip/hip_runtime.h>
#include <hip/hip_bf16.h>

using bf16 = __hip_bfloat16;
typedef short bf16x8 __attribute__((ext_vector_type(8)));
typedef float f32x4 __attribute__((ext_vector_type(4)));

#define DD 256
#define MTOT 65536   // B*QH*QW = 16*64*64

static __device__ __forceinline__ short f2bs(float f) {
    bf16 h = __float2bfloat16(f);          // RNE
    return *reinterpret_cast<short*>(&h);
}
static __device__ __forceinline__ float bs2f(short s) {
    unsigned u = (unsigned)(unsigned short)s << 16;
    return __uint_as_float(u);
}

// Pre-swizzled BT layout: element (n = output col, k) lives at flat index
//   n*256 + (((k>>3) ^ (n&7)) << 3 | (k&7))
// XOR only touches the low 3 bits of the 16B-granule index, so each 64-k
// (128B) slice of a row is swizzle-closed -> K-sliced LDS staging is a
// linear copy of global [n*256 + s*64, +64) per row.
static __device__ __forceinline__ int swz_idx(int n, int k) {
    return n * 256 + ((((k >> 3) ^ (n & 7)) << 3) | (k & 7));
}

// ---------------- K0: convert+transpose+swizzle weights (f32 -> bf16) ----------------
__global__ __launch_bounds__(256) void k_transpose(
    const float* __restrict__ Wb, const float* __restrict__ Wk, const float* __restrict__ Wm,
    const float* __restrict__ Woff, const float* __restrict__ WA,
    bf16* __restrict__ WbT, bf16* __restrict__ WkT, bf16* __restrict__ WmT,
    bf16* __restrict__ WoffAT)
{
    int idx = blockIdx.x * 256 + threadIdx.x;
    if (idx < 3 * 65536) {
        int which = idx >> 16, e = idx & 65535;
        int i = e >> 8, j = e & 255;               // in[i][j]: i = k, j = n
        const float* src = which == 0 ? Wb : (which == 1 ? Wk : Wm);
        bf16*        dst = which == 0 ? WbT : (which == 1 ? WkT : WmT);
        dst[swz_idx(j, i)] = __float2bfloat16(src[e]);
    } else {
        int e = idx - 3 * 65536;
        if (e < 96 * 256) {
            int j = e >> 8, i = e & 255;           // out row j = n (0..95), k = i
            WoffAT[swz_idx(j, i)] = __float2bfloat16((j < 64) ? Woff[i * 64 + j]
                                                              : WA[i * 32 + (j - 64)]);
        }
    }
}

// ---------------- LDS-staged MFMA mainloop ----------------
// Block: 256 thr = 4 waves; covers 64 A-rows x NCOLS output cols.
// wave w: rows row0 + (w>>1)*32 .. +31 ; cols (w&1)*NTW*16 .. (+NTW*16).
// BTswz: pre-swizzled [NCOLS][256]; Bs: shared [NCOLS*64] (one 64-k slice).
// mfma_f32_16x16x32_bf16 layouts (m89/m91-verified):
//   A-frag: row = lane&15, k = (lane>>4)*8 + e ;  B-frag: col = lane&15, same k
//   C/D   : col = lane&15, row = (lane>>4)*4 + reg
template <int NTW, int NCOLS, bool AF32>
static __device__ __forceinline__ void gemm_lds_mainloop(
    const void* __restrict__ Av, const bf16* __restrict__ BTswz,
    bf16* __restrict__ Bs, int row0, int tid, f32x4 (&acc)[2][NTW])
{
    const int wave = tid >> 6, lane = tid & 63;
    const int rg = wave >> 1, cg = wave & 1;
    const int rsub = lane & 15, kg = lane >> 4;
    const int arow = row0 + rg * 32 + rsub;
    constexpr int G16   = NCOLS * 8;       // 16B granules per 64-k slice
    constexpr int ITERS = G16 / 256;
#pragma unroll
    for (int s = 0; s < 4; ++s) {
        __syncthreads();                   // previous slice fully consumed
#pragma unroll
        for (int c = 0; c < ITERS; ++c) {  // linear copy: global swz -> LDS
            int i16 = c * 256 + tid;
            int n = i16 >> 3, lg = i16 & 7;
            *(bf16x8*)(Bs + i16 * 8) = *(const bf16x8*)(BTswz + n * 256 + s * 64 + lg * 8);
        }
        __syncthreads();
#pragma unroll
        for (int kkl = 0; kkl < 2; ++kkl) {
            const int k0 = s * 64 + kkl * 32 + kg * 8;
            bf16x8 a0, a1;
            if constexpr (AF32) {
                const float* ap = (const float*)Av + (size_t)arow * DD + k0;
                f32x4 v0 = *(const f32x4*)ap;
                f32x4 v1 = *(const f32x4*)(ap + 4);
                f32x4 w0 = *(const f32x4*)(ap + 16 * DD);
                f32x4 w1 = *(const f32x4*)(ap + 16 * DD + 4);
#pragma unroll
                for (int e = 0; e < 4; ++e) {
                    a0[e] = f2bs(v0[e]); a0[e + 4] = f2bs(v1[e]);
                    a1[e] = f2bs(w0[e]); a1[e + 4] = f2bs(w1[e]);
                }
            } else {
                const bf16* ap = (const bf16*)Av + (size_t)arow * DD + k0;
                a0 = *(const bf16x8*)ap;
                a1 = *(const bf16x8*)(ap + 16 * DD);
            }
            const int lg = kkl * 4 + kg;   // unswizzled local granule of this k-group
#pragma unroll
            for (int nt = 0; nt < NTW; ++nt) {
                int n = cg * (NTW * 16) + nt * 16 + rsub;
                bf16x8 b = *(const bf16x8*)(Bs + n * 64 + ((lg ^ (n & 7)) << 3));
                acc[0][nt] = __builtin_amdgcn_mfma_f32_16x16x32_bf16(a0, b, acc[0][nt], 0, 0, 0);
                acc[1][nt] = __builtin_amdgcn_mfma_f32_16x16x32_bf16(a1, b, acc[1][nt], 0, 0, 0);
            }
        }
    }
}

// ---------------- K1: sq = src_query @ Wb + bb  -> bf16 [65536][256] ----------------
__global__ __launch_bounds__(256) void k_gemm_sq(
    const float* __restrict__ src, const bf16* __restrict__ WbT,
    const float* __restrict__ bb, bf16* __restrict__ sq)
{
    __shared__ __align__(16) bf16 Bs[256 * 64];
    int tid = threadIdx.x, lane = tid & 63, wave = tid >> 6;
    int row0 = blockIdx.x * 64;
    f32x4 acc[2][8] = {};
    gemm_lds_mainloop<8, 256, true>(src, WbT, Bs, row0, tid, acc);
    int col = lane & 15;
    int jbase = (wave & 1) * 128;
    int rb = row0 + (wave >> 1) * 32 + ((lane >> 4) << 2);
#pragma unroll
    for (int mt = 0; mt < 2; ++mt)
#pragma unroll
        for (int nt = 0; nt < 8; ++nt) {
            int j = jbase + nt * 16 + col;
            float bias = bb[j];
#pragma unroll
            for (int r = 0; r < 4; ++r)
                sq[(size_t)(rb + mt * 16 + r) * DD + j] =
                    __float2bfloat16(acc[mt][nt][r] + bias);
        }
}

// ---------------- K2: [off | A] = sq @ WoffAT^T + bias ; softmax(A) over K=4 per head ----
__global__ __launch_bounds__(256) void k_gemm_offA(
    const bf16* __restrict__ sq, const bf16* __restrict__ WoffAT,
    const float* __restrict__ boff, const float* __restrict__ bA,
    float* __restrict__ off_ws, float* __restrict__ A_ws)
{
    __shared__ __align__(16) bf16 Bs[96 * 64];
    int tid = threadIdx.x, lane = tid & 63, wave = tid >> 6;
    int row0 = blockIdx.x * 64;
    f32x4 acc[2][3] = {};
    gemm_lds_mainloop<3, 96, false>(sq, WoffAT, Bs, row0, tid, acc);
    int col = lane & 15;
    int jbase = (wave & 1) * 48;
    int rb = row0 + (wave >> 1) * 32 + ((lane >> 4) << 2);
#pragma unroll
    for (int mt = 0; mt < 2; ++mt) {
#pragma unroll
        for (int nt = 0; nt < 3; ++nt) {
            int j = jbase + nt * 16 + col;          // wave-uniform side of 64 per (cg,nt)
            if (j < 64) {                           // offsets
                float bias = boff[j];
#pragma unroll
                for (int r = 0; r < 4; ++r) {
                    int m = rb + mt * 16 + r;
                    off_ws[(size_t)m * 64 + j] = acc[mt][nt][r] + bias;
                }
            } else {                                // A logits, ac = j-64 in 0..31
                int ac = j - 64;                    // head = ac>>2, slot = ac&3
                float bias = bA[ac];
#pragma unroll
                for (int r = 0; r < 4; ++r) {
                    int m = rb + mt * 16 + r;
                    float v  = acc[mt][nt][r] + bias;
                    // lanes l^1, l^2 hold the same head's other 3 slots
                    float mx = fmaxf(v, __shfl_xor(v, 1));
                    mx       = fmaxf(mx, __shfl_xor(mx, 2));
                    float e  = __expf(v - mx);
                    float su = e + __shfl_xor(e, 1);
                    su      += __shfl_xor(su, 2);
                    A_ws[(size_t)m * 32 + ac] = e / su;
                }
            }
        }
    }
}

// ---------------- K3: kf = keys @ Wk + bk -> bf16 head-split [(b*8+h)*4096 + pix][32] ----
__global__ __launch_bounds__(256) void k_gemm_kf(
    const float* __restrict__ keys, const bf16* __restrict__ WkT,
    const float* __restrict__ bk, bf16* __restrict__ kf)
{
    __shared__ __align__(16) bf16 Bs[256 * 64];
    int tid = threadIdx.x, lane = tid & 63, wave = tid >> 6;
    int row0 = blockIdx.x * 64;
    f32x4 acc[2][8] = {};
    gemm_lds_mainloop<8, 256, true>(keys, WkT, Bs, row0, tid, acc);
    int col = lane & 15;
    int jbase = (wave & 1) * 128;
    int rb = row0 + (wave >> 1) * 32 + ((lane >> 4) << 2);
#pragma unroll
    for (int mt = 0; mt < 2; ++mt)
#pragma unroll
        for (int nt = 0; nt < 8; ++nt) {
            int j = jbase + nt * 16 + col;         // head h=j>>5, channel c=j&31
            float bias = bk[j];
#pragma unroll
            for (int r = 0; r < 4; ++r) {
                int m = rb + mt * 16 + r;          // b = m>>12, pix = m&4095
                size_t dst = (((size_t)(m >> 12) * 8 + (j >> 5)) * 4096 + (m & 4095)) * 32 + (j & 31);
                kf[dst] = __float2bfloat16(acc[mt][nt][r] + bias);
            }
        }
}

// ---------------- K4: bilinear gather + weighted sum -> feat bf16 [65536][256] ----------------
// Block = 8 queries x 8 heads x 4 channel-groups (of 8 ch). Each lane: 16B bf16x8
// corner loads, branchless zero-padding via multiplicative validity masks.
__global__ __launch_bounds__(256) void k_sample(
    const float* __restrict__ ref_point, const float* __restrict__ off_ws,
    const float* __restrict__ A_ws, const bf16* __restrict__ kf,
    bf16* __restrict__ feat)
{
    int t  = threadIdx.x;
    int q  = t >> 5;             // 0..7
    int h  = (t >> 2) & 7;       // 0..7
    int cg = t & 3;              // 0..3 -> channels cg*8..cg*8+7
    int m  = blockIdx.x * 8 + q;
    int b  = m >> 12, pix = m & 4095;
    int rbatch = (b * 8 + h) & 15;      // faithful: tile() => ref batch = (b*H+h) % B
    const float* rp = ref_point + ((size_t)rbatch * 4096 + pix) * 2;
    float rx = rp[0] * 63.0f;
    float ry = rp[1] * 63.0f;
    const bf16* kfh = kf + ((size_t)(b * 8 + h) * 4096) * 32 + cg * 8;
    float acc[8] = {};
#pragma unroll
    for (int k = 0; k < 4; ++k) {
        const float* op = off_ws + (size_t)m * 64 + (h * 4 + k) * 2;
        float ox = op[0], oy = op[1];
        float a  = A_ws[(size_t)m * 32 + h * 4 + k];
        float px = (rx + ox) * (64.0f / 63.0f) - 0.5f;   // grid_sample unnormalize, align_corners=False
        float py = (ry + oy) * (64.0f / 63.0f) - 0.5f;
        float x0 = floorf(px), y0 = floorf(py);
        float wx1 = px - x0, wy1 = py - y0;
        int xi = (int)x0, yi = (int)y0;
        // validity folded into weights (padding_mode='zeros'), premultiplied by a
        float ax0 = (1.f - wx1) * ((xi     >= 0 && xi     < 64) ? 1.f : 0.f);
        float ax1 = wx1         * ((xi + 1 >= 0 && xi + 1 < 64) ? 1.f : 0.f);
        float ay0 = (1.f - wy1) * ((yi     >= 0 && yi     < 64) ? a : 0.f);
        float ay1 = wy1         * ((yi + 1 >= 0 && yi + 1 < 64) ? a : 0.f);
        int xc0 = min(max(xi, 0), 63),      xc1 = min(max(xi + 1, 0), 63);
        int yc0 = min(max(yi, 0), 63) * 64, yc1 = min(max(yi + 1, 0), 63) * 64;
        bf16x8 v00 = *(const bf16x8*)(kfh + (yc0 + xc0) * 32);
        bf16x8 v01 = *(const bf16x8*)(kfh + (yc0 + xc1) * 32);
        bf16x8 v10 = *(const bf16x8*)(kfh + (yc1 + xc0) * 32);
        bf16x8 v11 = *(const bf16x8*)(kfh + (yc1 + xc1) * 32);
        float w00 = ax0 * ay0, w01 = ax1 * ay0, w10 = ax0 * ay1, w11 = ax1 * ay1;
#pragma unroll
        for (int e = 0; e < 8; ++e) {
            acc[e] += w00 * bs2f(v00[e]) + w01 * bs2f(v01[e])
                    + w10 * bs2f(v10[e]) + w11 * bs2f(v11[e]);
        }
    }
    bf16x8 o;
#pragma unroll
    for (int e = 0; e < 8; ++e) o[e] = f2bs(acc[e]);
    *(bf16x8*)(feat + (size_t)m * DD + h * 32 + cg * 8) = o;
}

// ---------------- K5: out = feat @ Wm + bm -> f32 ----------------
__global__ __launch_bounds__(256) void k_gemm_out(
    const bf16* __restrict__ feat, const bf16* __restrict__ WmT,
    const float* __restrict__ bm, float* __restrict__ out)
{
    __shared__ __align__(16) bf16 Bs[256 * 64];
    int tid = threadIdx.x, lane = tid & 63, wave = tid >> 6;
    int row0 = blockIdx.x * 64;
    f32x4 acc[2][8] = {};
    gemm_lds_mainloop<8, 256, false>(feat, WmT, Bs, row0, tid, acc);
    int col = lane & 15;
    int jbase = (wave & 1) * 128;
    int rb = row0 + (wave >> 1) * 32 + ((lane >> 4) << 2);
#pragma unroll
    for (int mt = 0; mt < 2; ++mt)
#pragma unroll
        for (int nt = 0; nt < 8; ++nt) {
            int j = jbase + nt * 16 + col;
            float bias = bm[j];
#pragma unroll
            for (int r = 0; r < 4; ++r)
                out[(size_t)(rb + mt * 16 + r) * DD + j] =
                    acc[mt][nt][r] + bias;
        }
}

extern "C" void kernel_launch(void* const* d_in, const int* in_sizes, int n_in,
                              void* d_out, int out_size, void* d_ws, size_t ws_size,
                              hipStream_t stream)
{
    (void)in_sizes; (void)n_in; (void)out_size; (void)ws_size;
    // setup_inputs order (all float32):
    // 0 query (unused) 1 keys 2 ref_point 3 src_query 4 Wq 5 bq 6 Wb 7 bb
    // 8 Wk 9 bk 10 Woff 11 boff 12 WA 13 bA 14 Wm 15 bm
    const float* keys = (const float*)d_in[1];
    const float* refp = (const float*)d_in[2];
    const float* srcq = (const float*)d_in[3];
    const float* Wb   = (const float*)d_in[6];
    const float* bb   = (const float*)d_in[7];
    const float* Wk   = (const float*)d_in[8];
    const float* bk   = (const float*)d_in[9];
    const float* Woff = (const float*)d_in[10];
    const float* boff = (const float*)d_in[11];
    const float* WA   = (const float*)d_in[12];
    const float* bA   = (const float*)d_in[13];
    const float* Wm   = (const float*)d_in[14];
    const float* bm   = (const float*)d_in[15];

    char* ws = (char*)d_ws;
    bf16*  WbT    = (bf16*)(ws + 0);                    // 128 KiB (swizzled)
    bf16*  WkT    = (bf16*)(ws + 131072);               // 128 KiB (swizzled)
    bf16*  WmT    = (bf16*)(ws + 262144);               // 128 KiB (swizzled)
    bf16*  WoffAT = (bf16*)(ws + 393216);               // 48 KiB  [96][256] (swizzled)
    bf16*  sq_ws  = (bf16*)(ws + 442368);               // 32 MiB  [65536][256]
    bf16*  kf_ws  = (bf16*)(ws + 442368 + 33554432ull);             // 32 MiB
    bf16*  feat_ws= (bf16*)(ws + 442368 + 2ull * 33554432ull);      // 32 MiB
    float* off_ws = (float*)(ws + 442368 + 3ull * 33554432ull);     // 16 MiB  [65536][64]
    float* A_ws   = (float*)(ws + 442368 + 3ull * 33554432ull + 16777216ull); // 8 MiB [65536][32]

    float* out = (float*)d_out;

    k_transpose<<<864, 256, 0, stream>>>(Wb, Wk, Wm, Woff, WA, WbT, WkT, WmT, WoffAT);
    k_gemm_sq  <<<1024, 256, 0, stream>>>(srcq, WbT, bb, sq_ws);
    k_gemm_kf  <<<1024, 256, 0, stream>>>(keys, WkT, bk, kf_ws);
    k_gemm_offA<<<1024, 256, 0, stream>>>(sq_ws, WoffAT, boff, bA, off_ws, A_ws);
    k_sample   <<<8192, 256, 0, stream>>>(refp, off_ws, A_ws, kf_ws, feat_ws);
    k_gemm_out <<<1024, 256, 0, stream>>>(feat_ws, WmT, bm, out);
}